// Round 4
// baseline (115.326 us; speedup 1.0000x reference)
//
#include <hip/hip_runtime.h>
#include <math.h>

// Problem constants (fixed by the reference)
#define N_NODES 50000
#define N_EDGES 800000
#define FN_DIM 16
#define HD 64
#define T_CAP 8192     // cap on |need1| (expected ~290)  = layer-0 targets
#define T2_CAP 512     // cap on |need2| (expected ~17)   = layer-1 targets
#define MAXDEG 128     // cap on in-degree (Poisson(16))

// ---------- wave-64 helpers ----------
__device__ __forceinline__ float wsum64(float v) {
    #pragma unroll
    for (int o = 1; o < 64; o <<= 1) v += __shfl_xor(v, o);
    return v;
}
__device__ __forceinline__ float wmax64(float v) {
    #pragma unroll
    for (int o = 1; o < 64; o <<= 1) v = fmaxf(v, __shfl_xor(v, o));
    return v;
}
__device__ __forceinline__ float lrelu02(float v) { return v > 0.f ? v : 0.2f * v; }

// ---------- zero the flag/counter zone (replaces 42us rocclr fill) ----------
__global__ void k_zero(int4* __restrict__ p, int n4) {
    int i = blockIdx.x * blockDim.x + threadIdx.x;
    if (i < n4) p[i] = make_int4(0, 0, 0, 0);
}

// ---------- discovery (int4-vectorized, 4 edges/thread) ----------
__global__ void k_mark2(const int* __restrict__ ei, int* need1, int* need2) {
    int i = blockIdx.x * blockDim.x + threadIdx.x;
    if (i == 0) { need1[0] = 1; need2[0] = 1; }
    if (i >= N_EDGES / 4) return;
    int4 d4 = ((const int4*)(ei + N_EDGES))[i];
    int4 s4 = ((const int4*)ei)[i];
    if (d4.x == 0) { need2[s4.x] = 1; need1[s4.x] = 1; }
    if (d4.y == 0) { need2[s4.y] = 1; need1[s4.y] = 1; }
    if (d4.z == 0) { need2[s4.z] = 1; need1[s4.z] = 1; }
    if (d4.w == 0) { need2[s4.w] = 1; need1[s4.w] = 1; }
}
__global__ void k_mark1(const int* __restrict__ ei, const int* __restrict__ need2, int* need1) {
    int i = blockIdx.x * blockDim.x + threadIdx.x;
    if (i >= N_EDGES / 4) return;
    int4 d4 = ((const int4*)(ei + N_EDGES))[i];
    int4 s4 = ((const int4*)ei)[i];
    if (need2[d4.x]) need1[s4.x] = 1;
    if (need2[d4.y]) need1[s4.y] = 1;
    if (need2[d4.z]) need1[s4.z] = 1;
    if (need2[d4.w]) need1[s4.w] = 1;
}

// ---------- compact node lists + idx maps; blocks 0..5 also compute ps/pd vecs ----------
__global__ void k_compact(const int* __restrict__ need1, const int* __restrict__ need2,
                          int* list1, int* list2, int* idx1, int* idx2, int* cnt,
                          const float* __restrict__ Wg, const float* __restrict__ atts,
                          const float* __restrict__ attd, float* __restrict__ pvec) {
    int i = blockIdx.x * blockDim.x + threadIdx.x;
    if (i < N_NODES) {
        if (need1[i]) { int p = atomicAdd(&cnt[0], 1); if (p < T_CAP)  { list1[p] = i; idx1[i] = p; } }
        if (need2[i]) { int p = atomicAdd(&cnt[1], 1); if (p < T2_CAP) { list2[p] = i; idx2[i] = p; } }
    }
    // ps[l] = Wg[l]^T att_src[l], pd[l] = Wg[l]^T att_dst[l]  (6 tasks on blocks 0..5)
    if (blockIdx.x < 6 && threadIdx.x < 64) {
        int task = blockIdx.x; int l = task >> 1; int which = task & 1;
        const float* att = which ? attd : atts;
        float av = att[l * 64 + threadIdx.x];
        const float* wg = Wg + l * 4096 + threadIdx.x * 64;
        float acc = 0.f;
        #pragma unroll 8
        for (int c = 0; c < 64; c++) acc += wg[c] * __shfl(av, c);
        pvec[l * 128 + which * 64 + threadIdx.x] = acc;
    }
}

__global__ void k_bucket(const int* __restrict__ ei, const int* __restrict__ need1,
                         const int* __restrict__ need2,
                         const int* __restrict__ idx1, const int* __restrict__ idx2,
                         int* eb1, int* deg1, int* eb2, int* deg2, int* eb3, int* deg3) {
    int i = blockIdx.x * blockDim.x + threadIdx.x;
    if (i >= N_EDGES / 4) return;
    int4 d4 = ((const int4*)(ei + N_EDGES))[i];
    int4 s4 = ((const int4*)ei)[i];
    int ds[4] = {d4.x, d4.y, d4.z, d4.w};
    int ss[4] = {s4.x, s4.y, s4.z, s4.w};
    #pragma unroll
    for (int c = 0; c < 4; c++) {
        int d = ds[c], s = ss[c];
        if (need1[d]) {
            int t = idx1[d];
            if ((unsigned)t < T_CAP) { int p = atomicAdd(&deg1[t], 1); if (p < MAXDEG) eb1[t * MAXDEG + p] = s; }
        }
        if (need2[d]) {
            int t = idx2[d];
            if ((unsigned)t < T2_CAP) { int p = atomicAdd(&deg2[t], 1); if (p < MAXDEG) eb2[t * MAXDEG + p] = s; }
        }
        if (d == 0) { int p = atomicAdd(deg3, 1); if (p < MAXDEG) eb3[p] = s; }
    }
}

// ---------- node feature (single node): layer 0 encodes from x, later layers load h ----------
template<int LM>
__device__ __forceinline__ float node_h1(int i, int lane,
    const float* __restrict__ x, const float* __restrict__ Wn, const float* __restrict__ bn,
    const float* __restrict__ gn, const float* __restrict__ betan,
    const float* __restrict__ hin) {
    if (LM == 0) {
        float xv = x[i * FN_DIM + (lane & 15)];
        float acc = bn[lane];
        #pragma unroll
        for (int k = 0; k < FN_DIM; k++) acc += __shfl(xv, k) * Wn[k * HD + lane];
        float v = fmaxf(acc, 0.f);
        float mu = wsum64(v) * (1.f / 64.f);
        float d = v - mu;
        float var = wsum64(d * d) * (1.f / 64.f);
        return d * rsqrtf(var + 1e-5f) * gn[lane] + betan[lane];
    } else {
        return hin[i * HD + lane];
    }
}

// ---------- fully fused layer: block per target, 4 waves, 4 edges/wave/pass ----------
// EdgeConv: m = Wc2.relu(Wc1a.h_t + Wc1b.h_s + bc1) + bc2, segment-max
// GAT (factored): logit_j = lrelu(ps.h_j + pd.h_t); att = Wg.(sum_j alpha_j h_j) + bg
// out: h' = relu(h_t + agg + att)
template<int LM>
__global__ __launch_bounds__(256, 1) void k_layer(
    const float* __restrict__ x, const float* __restrict__ Wn, const float* __restrict__ bn,
    const float* __restrict__ gn, const float* __restrict__ betan,
    const float* __restrict__ hin,
    const float* __restrict__ Wc1, const float* __restrict__ bc1,
    const float* __restrict__ Wc2, const float* __restrict__ bc2,
    const float* __restrict__ Wg, const float* __restrict__ pvec,
    const float* __restrict__ bgv,
    const int* __restrict__ tlist, const int* __restrict__ cntp, int tcap,
    const int* __restrict__ eb, const int* __restrict__ deg,
    float* __restrict__ hout,
    const float* __restrict__ Wq1, const float* __restrict__ bq1,
    const float* __restrict__ gq, const float* __restrict__ betaq,
    const float* __restrict__ Wq2, const float* __restrict__ bq2,
    const float* __restrict__ Wv1, const float* __restrict__ bv1,
    const float* __restrict__ gv, const float* __restrict__ betav,
    const float* __restrict__ Wv2, const float* __restrict__ bv2)
{
    __shared__ float hsc[MAXDEG][HD];     // 32 KB: h_s per edge (for softmax-weighted sum)
    __shared__ float ec[MAXDEG];          // per-edge attention logit
    __shared__ float redA[4][HD];         // per-wave EdgeConv max partials
    __shared__ float redH[4][HD];         // per-wave weighted-h partials
    __shared__ float sws[4];
    __shared__ float sOut[HD];
    __shared__ float sEm;

    int lane = threadIdx.x & 63;
    int wv = threadIdx.x >> 6;
    int ntgt = (LM == 2) ? 1 : min(cntp[0], tcap);
    float ps = pvec[lane], pd = pvec[64 + lane];

    for (int w = blockIdx.x; w < ntgt; w += gridDim.x) {
        int t = (LM == 2) ? 0 : tlist[w];
        // ---- target features (computed redundantly by each wave; no barrier needed)
        float hval = node_h1<LM>(t, lane, x, Wn, bn, gn, betan, hin);
        float uval = bc1[lane];
        #pragma unroll 8
        for (int k = 0; k < HD; k++) uval += __shfl(hval, k) * Wc1[k * HD + lane];
        float a_st = wsum64(hval * ps);
        float a_dt = wsum64(hval * pd);
        float es = lrelu02(a_st + a_dt);    // self-loop logit

        int dg = deg[(LM == 2) ? 0 : w]; if (dg > MAXDEG) dg = MAXDEG;
        float aggw = -INFINITY;

        for (int base = wv * 4; base < dg; base += 16) {
            int ne = dg - base; if (ne > 4) ne = 4;
            float hs[4] = {0.f, 0.f, 0.f, 0.f};
            if (LM == 0) {
                float xv[4] = {0.f, 0.f, 0.f, 0.f};
                #pragma unroll
                for (int e = 0; e < 4; e++)
                    if (e < ne) xv[e] = x[eb[w * MAXDEG + base + e] * FN_DIM + (lane & 15)];
                #pragma unroll
                for (int e = 0; e < 4; e++) hs[e] = bn[lane];
                #pragma unroll
                for (int k = 0; k < FN_DIM; k++) {
                    float wn = Wn[k * HD + lane];
                    #pragma unroll
                    for (int e = 0; e < 4; e++) hs[e] += __shfl(xv[e], k) * wn;
                }
                #pragma unroll
                for (int e = 0; e < 4; e++) {
                    float v = fmaxf(hs[e], 0.f);
                    float mu = wsum64(v) * (1.f / 64.f);
                    float d = v - mu;
                    float var = wsum64(d * d) * (1.f / 64.f);
                    hs[e] = d * rsqrtf(var + 1e-5f) * gn[lane] + betan[lane];
                }
            } else {
                #pragma unroll
                for (int e = 0; e < 4; e++)
                    if (e < ne) hs[e] = hin[eb[w * MAXDEG + base + e] * HD + lane];
            }
            // stash h_s + logit
            #pragma unroll
            for (int e = 0; e < 4; e++) {
                if (e < ne) {
                    hsc[base + e][lane] = hs[e];
                    float as = wsum64(hs[e] * ps);
                    if (lane == 0) ec[base + e] = lrelu02(as + a_dt);
                }
            }
            // v = Wc1b . h_s (batched over 4 edges per weight-column load)
            float v[4] = {0.f, 0.f, 0.f, 0.f};
            #pragma unroll 8
            for (int k = 0; k < HD; k++) {
                float wc = Wc1[(HD + k) * HD + lane];
                #pragma unroll
                for (int e = 0; e < 4; e++) v[e] += __shfl(hs[e], k) * wc;
            }
            float hid[4];
            #pragma unroll
            for (int e = 0; e < 4; e++) hid[e] = fmaxf(uval + v[e], 0.f);
            float m[4];
            #pragma unroll
            for (int e = 0; e < 4; e++) m[e] = bc2[lane];
            #pragma unroll 8
            for (int k = 0; k < HD; k++) {
                float wc2v = Wc2[k * HD + lane];
                #pragma unroll
                for (int e = 0; e < 4; e++) m[e] += __shfl(hid[e], k) * wc2v;
            }
            #pragma unroll
            for (int e = 0; e < 4; e++) if (e < ne) aggw = fmaxf(aggw, m[e]);
        }
        redA[wv][lane] = aggw;
        __syncthreads();

        // ---- softmax max (wave 0)
        if (wv == 0) {
            float mm = es;
            for (int j = lane; j < dg; j += 64) mm = fmaxf(mm, ec[j]);
            mm = wmax64(mm);
            if (lane == 0) sEm = mm;
        }
        __syncthreads();
        float em = sEm;

        // ---- weighted h-sum (all waves, edges strided)
        float hw = 0.f, wsv = 0.f;
        for (int j = wv; j < dg; j += 4) {
            float wj = expf(ec[j] - em);
            hw += wj * hsc[j][lane];
            wsv += wj;
        }
        redH[wv][lane] = hw;
        if (lane == 0) sws[wv] = wsv;
        __syncthreads();

        // ---- final combine (wave 0)
        if (wv == 0) {
            float wself = expf(es - em);
            float wsumT = sws[0] + sws[1] + sws[2] + sws[3] + wself;
            float hbar = (redH[0][lane] + redH[1][lane] + redH[2][lane] + redH[3][lane]
                          + wself * hval) / wsumT;
            float att = bgv[lane];
            #pragma unroll 8
            for (int k = 0; k < HD; k++) att += __shfl(hbar, k) * Wg[k * HD + lane];
            float agg = fmaxf(fmaxf(redA[0][lane], redA[1][lane]),
                              fmaxf(redA[2][lane], redA[3][lane]));
            if (dg == 0) agg = 0.f;   // PyG scatter-max: empty segment -> 0
            float hv = fmaxf(hval + agg + att, 0.f);
            if (LM == 2) sOut[lane] = hv;
            else hout[t * HD + lane] = hv;
        }
        if (LM == 2) {
            __syncthreads();
            float hvv = sOut[lane];
            if (wv == 0) {            // q head
                float acc = bq1[lane];
                #pragma unroll 8
                for (int k = 0; k < 64; k++) acc += __shfl(hvv, k) * Wq1[k * 64 + lane];
                float r = fmaxf(acc, 0.f);
                float mu = wsum64(r) * (1.f / 64.f);
                float d = r - mu;
                float var = wsum64(d * d) * (1.f / 64.f);
                float tq = d * rsqrtf(var + 1e-5f) * gq[lane] + betaq[lane];
                int s2 = lane & 31;
                float q = bq2[s2];
                #pragma unroll 8
                for (int k = 0; k < 64; k++) q += __shfl(tq, k) * Wq2[k * 32 + s2];
                if (lane < 32) hout[lane] = q;
            } else if (wv == 1) {     // value head
                float accv = bv1[lane];
                #pragma unroll 8
                for (int k = 0; k < 64; k++) accv += __shfl(hvv, k) * Wv1[k * 64 + lane];
                float rv = fmaxf(accv, 0.f);
                float muv = wsum64(rv) * (1.f / 64.f);
                float dv = rv - muv;
                float varv = wsum64(dv * dv) * (1.f / 64.f);
                float tv = dv * rsqrtf(varv + 1e-5f) * gv[lane] + betav[lane];
                float vsum = wsum64(tv * Wv2[lane]);
                if (lane == 0) hout[32] = vsum + bv2[0];
            }
        }
        __syncthreads();
    }
}

extern "C" void kernel_launch(void* const* d_in, const int* in_sizes, int n_in,
                              void* d_out, int out_size, void* d_ws, size_t ws_size,
                              hipStream_t stream) {
    const float* x        = (const float*)d_in[0];
    const int*   ei       = (const int*)d_in[1];
    // d_in[2] edge_attr and d_in[7..10] (edge encoder) are dead code in the reference
    const float* Wn       = (const float*)d_in[3];
    const float* bn       = (const float*)d_in[4];
    const float* gn       = (const float*)d_in[5];
    const float* betan    = (const float*)d_in[6];
    const float* Wc1      = (const float*)d_in[11];
    const float* bc1      = (const float*)d_in[12];
    const float* Wc2      = (const float*)d_in[13];
    const float* bc2      = (const float*)d_in[14];
    const float* Wg       = (const float*)d_in[15];
    const float* att_src  = (const float*)d_in[16];
    const float* att_dst  = (const float*)d_in[17];
    const float* bg       = (const float*)d_in[18];
    const float* Wq1      = (const float*)d_in[19];
    const float* bq1      = (const float*)d_in[20];
    const float* gq       = (const float*)d_in[21];
    const float* betaq    = (const float*)d_in[22];
    const float* Wq2      = (const float*)d_in[23];
    const float* bq2      = (const float*)d_in[24];
    const float* Wv1      = (const float*)d_in[25];
    const float* bv1      = (const float*)d_in[26];
    const float* gv       = (const float*)d_in[27];
    const float* betav    = (const float*)d_in[28];
    const float* Wv2      = (const float*)d_in[29];
    const float* bv2      = (const float*)d_in[30];

    // ---- workspace layout (~31 MB)
    float* hB   = (float*)d_ws;                      // h1, N*64
    float* hA   = hB + (size_t)N_NODES * HD;         // h2, N*64
    int* need1  = (int*)(hA + (size_t)N_NODES * HD); // zero-zone start (16B aligned)
    int* need2  = need1 + N_NODES;
    int* deg1   = need2 + N_NODES;                   // T_CAP
    int* deg2   = deg1 + T_CAP;                      // T2_CAP
    int* deg3   = deg2 + T2_CAP;                     // 4
    int* cnt    = deg3 + 4;                          // 8   (zero-zone end)
    int* idx1   = cnt + 8;                           // N
    int* idx2   = idx1 + N_NODES;                    // N
    int* list1  = idx2 + N_NODES;                    // T_CAP
    int* list2  = list1 + T_CAP;                     // T2_CAP
    int* eb1    = list2 + T2_CAP;                    // T_CAP*MAXDEG
    int* eb2    = eb1 + (size_t)T_CAP * MAXDEG;      // T2_CAP*MAXDEG
    int* eb3    = eb2 + (size_t)T2_CAP * MAXDEG;     // MAXDEG
    float* pvec = (float*)(eb3 + MAXDEG);            // 3*128 ps/pd vectors

    const int zero_ints = 2 * N_NODES + T_CAP + T2_CAP + 12;   // 108716, /4 exact
    const int n4 = zero_ints / 4;
    const int E4B = (N_EDGES / 4 + 255) / 256;       // 782 blocks
    const int NB = (N_NODES + 255) / 256;            // 196 blocks

    k_zero<<<(n4 + 255) / 256, 256, 0, stream>>>((int4*)need1, n4);
    k_mark2<<<E4B, 256, 0, stream>>>(ei, need1, need2);
    k_mark1<<<E4B, 256, 0, stream>>>(ei, need2, need1);
    k_compact<<<NB, 256, 0, stream>>>(need1, need2, list1, list2, idx1, idx2, cnt,
                                      Wg, att_src, att_dst, pvec);
    k_bucket<<<E4B, 256, 0, stream>>>(ei, need1, need2, idx1, idx2,
                                      eb1, deg1, eb2, deg2, eb3, deg3);

    // layer 0: targets list1 (~290), sources encoded from x on the fly -> hB
    k_layer<0><<<320, 256, 0, stream>>>(
        x, Wn, bn, gn, betan, (const float*)nullptr,
        Wc1 + 0 * 2 * HD * HD, bc1 + 0 * HD, Wc2 + 0 * HD * HD, bc2 + 0 * HD,
        Wg + 0 * HD * HD, pvec + 0 * 128, bg + 0 * HD,
        list1, cnt + 0, T_CAP, eb1, deg1, hB,
        Wq1, bq1, gq, betaq, Wq2, bq2, Wv1, bv1, gv, betav, Wv2, bv2);

    // layer 1: targets list2 (~17), h from hB -> hA
    k_layer<1><<<32, 256, 0, stream>>>(
        x, Wn, bn, gn, betan, hB,
        Wc1 + 1 * 2 * HD * HD, bc1 + 1 * HD, Wc2 + 1 * HD * HD, bc2 + 1 * HD,
        Wg + 1 * HD * HD, pvec + 1 * 128, bg + 1 * HD,
        list2, cnt + 1, T2_CAP, eb2, deg2, hA,
        Wq1, bq1, gq, betaq, Wq2, bq2, Wv1, bv1, gv, betav, Wv2, bv2);

    // layer 2: target {0}, h from hA -> heads -> d_out
    k_layer<2><<<1, 256, 0, stream>>>(
        x, Wn, bn, gn, betan, hA,
        Wc1 + 2 * 2 * HD * HD, bc1 + 2 * HD, Wc2 + 2 * HD * HD, bc2 + 2 * HD,
        Wg + 2 * HD * HD, pvec + 2 * 128, bg + 2 * HD,
        (const int*)nullptr, cnt + 1, 1, eb3, deg3, (float*)d_out,
        Wq1, bq1, gq, betaq, Wq2, bq2, Wv1, bv1, gv, betav, Wv2, bv2);
}